// Round 12
// baseline (117.014 us; speedup 1.0000x reference)
//
#include <hip/hip_runtime.h>

// PostProcessor3D: threshold(>0.9) + 5x5x5 stride-1 maxpool + strict-local-max
// mask on [64,512,512] fp32.
//
// R12: producer-side W-max. R11's consume chain was 10 ds_reads (5 wasted on
// halo) + 4 dependent shuffles. Now each staging thread loads its quad AND
// both neighbor quads from global (3 overlapping b128 loads; overlap hits
// L1/L2, HBM fetch unchanged), computes the 5-tap W-max in registers, and
// writes the W-maxed quad (wm) to LDS plus the raw center quad (cen).
// Consume = 5 ds_reads of wm (H-max) + 1 ds_read of cen. Zero shuffles,
// zero halo reads, 3x the in-flight global bytes.
//
// Rings: win[5] (HW-maxed slices t-4..t), cen_r[3] in registers (center
// slice t-2 at output time; LDS cen can't be used directly since the dbuf
// cycles every 2 slices). Loop fully unrolled -> all ring indices
// compile-time constants (no scratch spill; R3 lesson).
//
// One no-drain barrier (lgkmcnt only; global prefetch loads stay in flight;
// register deps get compiler vmcnt waits) per slice. Hazards: wm/cen
// write@stage(t) -> read@consume(t): B(t). read@consume(t) -> rewrite@
// stage(t+2): B(t+1). OK with a single barrier + double buffer.
//
// Raw-max trick (R11, verified): thresh commutes with max and the center is
// in its own window, so out = (c > 0.9 && c == rawmax5^3) ? c : 0 -- no
// thresholding in the hot loop. Zero-padding == -inf padding (values >= 0).
//
// Tile: W=64 x H=16, DCHUNK=16 -> grid 8x32x4 = 1024 blocks, 4/CU.
// Block-id layout is XCD-friendly: D/H-halo neighbor blocks are 256/8 ids
// apart -> same XCD under %8 dispatch -> halo re-reads are L2-local.

#define THRESH 0.9f

constexpr int D = 64, H = 512, W = 512;
constexpr int HW = H * W;
constexpr int TW = 64;                    // tile width in floats (16 quads)
constexpr int TH = 16;                    // tile height
constexpr int DCHUNK = 16;                // depth outputs per block
constexpr int HALO = 2;
constexpr int LROWS = TH + 2 * HALO;      // 20 staged rows
constexpr int WMC = 16;                   // wm cols (output quads)
constexpr int WM_S = WMC + 1;             // 17: de-phase rows
constexpr int CEN_S = 17;                 // cen stride (16 cols + pad)
constexpr int NS = DCHUNK + 2 * HALO;     // 20 slices per block

typedef float floatx4 __attribute__((ext_vector_type(4)));

__device__ __forceinline__ void barrier_no_drain() {
    asm volatile("s_waitcnt lgkmcnt(0)\n\ts_barrier" ::: "memory");
}

__device__ __forceinline__ float4 max4(float4 a, float4 b) {
    return make_float4(fmaxf(a.x, b.x), fmaxf(a.y, b.y),
                       fmaxf(a.z, b.z), fmaxf(a.w, b.w));
}

// 5-tap sliding max for middle quad b given (left a, mid b, right c).
// f0 = a.x; out[j] = max(f[2+j .. 6+j]).
__device__ __forceinline__ float4 wmax5(float4 a, float4 b, float4 c) {
    const float f2 = a.z, f3 = a.w, f4 = b.x, f5 = b.y, f6 = b.z, f7 = b.w;
    const float f8 = c.x, f9 = c.y;
    const float m45 = fmaxf(f4, f5);
    const float m56 = fmaxf(f5, f6);
    const float m345 = fmaxf(f3, m45);
    const float m456 = fmaxf(f4, m56);
    const float m567 = fmaxf(m56, f7);
    const float m678 = fmaxf(fmaxf(f6, f7), f8);
    float4 r;
    r.x = fmaxf(fmaxf(f2, f6), m345);
    r.y = fmaxf(fmaxf(f3, f7), m456);
    r.z = fmaxf(fmaxf(f4, f8), m567);
    r.w = fmaxf(fmaxf(f5, f9), m678);
    return r;
}

__global__ __launch_bounds__(256)
void peak3d_kernel(const float* __restrict__ in, float* __restrict__ out) {
    __shared__ float4 wm [2][LROWS * WM_S];   // W-maxed quads: 2x340 = 10880 B
    __shared__ float4 cen[2][TH * CEN_S];     // raw center quads: 2x272 = 8704 B

    const int tx = threadIdx.x;               // 0..15 (quad col)
    const int ty = threadIdx.y;               // 0..15 (row)
    const int tid = ty * 16 + tx;

    const int w0 = blockIdx.x * TW;
    const int h0 = blockIdx.y * TH;
    const int d0 = blockIdx.z * DCHUNK;

    // wm-quad map: 20 rows x 16 cols = 320 quads. Quad A: q=tid (rows 0..15);
    // quad B: q=256+tid for tid<64 (rows 16..19, wave 0 only -> uniform).
    const int rA = tid >> 4, cA = (tid & 15) + 1;     // c in 1..16
    const bool hasB = (tid < 64);
    const int rB = 16 + (tid >> 4);                   // 16..19 (tid<64)
    const int cB = cA;

    const int ghA = h0 + rA - HALO;           // always relevant row for A
    const int ghB = h0 + rB - HALO;
    const bool vAr_ = (unsigned)ghA < (unsigned)H;
    const bool vBr_ = hasB && ((unsigned)ghB < (unsigned)H);
    const int gwl = w0 + 4 * cA - 8;          // left neighbor quad
    const int gwm = w0 + 4 * cA - 4;          // own quad (always in [0,512))
    const int gwr = w0 + 4 * cA;              // right neighbor quad
    const bool vl = (unsigned)gwl < (unsigned)W;
    const bool vr = (unsigned)gwr < (unsigned)W;
    const size_t offAl = (size_t)(vAr_ ? ghA : 0) * W + (vl ? gwl : 0);
    const size_t offAm = (size_t)(vAr_ ? ghA : 0) * W + gwm;
    const size_t offAr = (size_t)(vAr_ ? ghA : 0) * W + (vr ? gwr : 0);
    const size_t offBl = (size_t)(vBr_ ? ghB : 0) * W + (vl ? gwl : 0);
    const size_t offBm = (size_t)(vBr_ ? ghB : 0) * W + gwm;
    const size_t offBr = (size_t)(vBr_ ? ghB : 0) * W + (vr ? gwr : 0);
    const bool vAl = vAr_ && vl, vAm = vAr_, vArr = vAr_ && vr;
    const bool vBl = vBr_ && vl, vBm = vBr_, vBrr = vBr_ && vr;

    const float4 zero4 = make_float4(0.f, 0.f, 0.f, 0.f);
    float4 win[5], cen_r[3];
#pragma unroll
    for (int k = 0; k < 5; ++k) win[k] = zero4;
#pragma unroll
    for (int k = 0; k < 3; ++k) cen_r[k] = zero4;

    auto ld4 = [&](size_t off) {
        return *reinterpret_cast<const float4*>(in + off);
    };
    // Load the 6 quads (3 for A, 3 for B) of slice dd into pf[0..5].
    auto loadStage = [&](int dd, float4* pf) {
#pragma unroll
        for (int i = 0; i < 6; ++i) pf[i] = zero4;
        if (dd >= 0 && dd < D) {              // wave-uniform (t, d0 uniform)
            const size_t sb = (size_t)dd * HW;
            if (vAl)  pf[0] = ld4(sb + offAl);
            if (vAm)  pf[1] = ld4(sb + offAm);
            if (vArr) pf[2] = ld4(sb + offAr);
            if (vBl)  pf[3] = ld4(sb + offBl);
            if (vBm)  pf[4] = ld4(sb + offBm);
            if (vBrr) pf[5] = ld4(sb + offBr);
        }
    };

    float4 pf[6];
    loadStage(d0 - HALO, pf);                 // prime slice 0

#pragma unroll
    for (int t = 0; t < NS; ++t) {            // fully unrolled: t constant
        const int buf = t & 1;

        // ---- stage: W-max in registers, write wm + cen ----
        {
            const float4 wA = wmax5(pf[0], pf[1], pf[2]);
            wm[buf][rA * WM_S + (cA - 1)] = wA;
            if (rA >= HALO)                   // staged rows 2..15 -> cen rows 0..13
                cen[buf][(rA - HALO) * CEN_S + (cA - 1)] = pf[1];
            if (hasB) {
                const float4 wB = wmax5(pf[3], pf[4], pf[5]);
                wm[buf][rB * WM_S + (cB - 1)] = wB;
                if (rB <= TH + HALO - 1)      // rows 16..17 -> cen rows 14..15
                    cen[buf][(rB - HALO) * CEN_S + (cB - 1)] = pf[4];
            }
        }
        // prefetch slice t+1 (consumed at stage of t+1; in flight across
        // the barrier + consume below)
        if (t + 1 < NS) loadStage(d0 - HALO + t + 1, pf);

        barrier_no_drain();                   // the only barrier per slice

        // ---- consume: H-max over 5 wm rows + center read ----
        {
            const float4* wp = &wm[buf][ty * WM_S + tx];
            const float4 hv = max4(max4(max4(wp[0 * WM_S], wp[1 * WM_S]),
                                        max4(wp[3 * WM_S], wp[4 * WM_S])),
                                   wp[2 * WM_S]);
            win[t % 5] = hv;                  // HW-max of slice t
            cen_r[t % 3] = cen[buf][ty * CEN_S + tx];   // raw center, slice t
        }

        // ---- D-max + strict-local-max + store (slices t-4..t) ----
        if (t >= 4) {
            const int dout = d0 + (t - 4);    // window center slice t-2
            const float4 mp = max4(max4(max4(win[0], win[1]),
                                        max4(win[2], win[3])), win[4]);
            const float4 c = cen_r[(t + 1) % 3];   // written at iter t-2
            floatx4 res;
            res.x = (c.x > THRESH && mp.x == c.x) ? c.x : 0.f;
            res.y = (c.y > THRESH && mp.y == c.y) ? c.y : 0.f;
            res.z = (c.z > THRESH && mp.z == c.z) ? c.z : 0.f;
            res.w = (c.w > THRESH && mp.w == c.w) ? c.w : 0.f;
            floatx4* op = reinterpret_cast<floatx4*>(
                out + (size_t)dout * HW + (size_t)(h0 + ty) * W + (w0 + 4 * tx));
            __builtin_nontemporal_store(res, op);
        }
    }
}

extern "C" void kernel_launch(void* const* d_in, const int* in_sizes, int n_in,
                              void* d_out, int out_size, void* d_ws, size_t ws_size,
                              hipStream_t stream) {
    const float* in = (const float*)d_in[0];
    float* out = (float*)d_out;
    dim3 grid(W / TW, H / TH, D / DCHUNK);    // 8 x 32 x 4 = 1024 blocks
    dim3 block(16, 16, 1);
    hipLaunchKernelGGL(peak3d_kernel, grid, block, 0, stream, in, out);
}